// Round 1
// baseline (1293.665 us; speedup 1.0000x reference)
//
#include <hip/hip_runtime.h>
#include <stdint.h>

typedef unsigned short ushort_t;
typedef __attribute__((ext_vector_type(8))) short bf16x8;   // 8 bf16 in 4 VGPRs
typedef __attribute__((ext_vector_type(4))) float f32x4;

// ---------- helpers ----------
__device__ __forceinline__ unsigned short f2b(float f) {
  unsigned u = __float_as_uint(f);
  u += 0x7fffu + ((u >> 16) & 1u);   // round-to-nearest-even
  return (unsigned short)(u >> 16);
}

__device__ __forceinline__ void async16(const void* g, void* l) {
  // dest = wave-uniform LDS base + lane*16 (pass uniform base)
  __builtin_amdgcn_global_load_lds(
      (const __attribute__((address_space(1))) void*)g,
      (__attribute__((address_space(3))) void*)l, 16, 0, 0);
}

// ---------- LayerNorm (fp32 in -> bf16 out), one block per row, C=1024 ----------
__global__ __launch_bounds__(256) void ln_kernel(
    const float* __restrict__ x, const float* __restrict__ g,
    const float* __restrict__ be, ushort_t* __restrict__ out) {
  const int C = 1024;
  int row = blockIdx.x;
  const float4* xr = (const float4*)(x + (size_t)row * C);
  int tid = threadIdx.x;
  float4 v = xr[tid];
  float s = v.x + v.y + v.z + v.w;
  float sq = v.x * v.x + v.y * v.y + v.z * v.z + v.w * v.w;
  for (int off = 32; off > 0; off >>= 1) {
    s += __shfl_xor(s, off);
    sq += __shfl_xor(sq, off);
  }
  __shared__ float ss[4], ssq[4];
  int wv = tid >> 6;
  if ((tid & 63) == 0) { ss[wv] = s; ssq[wv] = sq; }
  __syncthreads();
  s = ss[0] + ss[1] + ss[2] + ss[3];
  sq = ssq[0] + ssq[1] + ssq[2] + ssq[3];
  float mu = s * (1.f / C);
  float var = sq * (1.f / C) - mu * mu;
  float rs = rsqrtf(var + 1e-5f);
  float4 gv = ((const float4*)g)[tid];
  float4 bv = ((const float4*)be)[tid];
  ushort4 o;
  o.x = f2b((v.x - mu) * rs * gv.x + bv.x);
  o.y = f2b((v.y - mu) * rs * gv.y + bv.y);
  o.z = f2b((v.z - mu) * rs * gv.z + bv.z);
  o.w = f2b((v.w - mu) * rs * gv.w + bv.w);
  ((ushort4*)(out + (size_t)row * C))[tid] = o;
}

// ---------- batched transpose + fp32->bf16 cast: in (bz,R,Cin) -> out (bz,Cin,R) ----------
__global__ __launch_bounds__(256) void transpose_cast_kernel(
    const float* __restrict__ in, ushort_t* __restrict__ out, int R, int Cin) {
  __shared__ float tile[32][33];
  int bz = blockIdx.z;
  in += (size_t)bz * R * Cin;
  out += (size_t)bz * R * Cin;
  int c0 = blockIdx.x * 32, r0 = blockIdx.y * 32;
  int tx = threadIdx.x, ty = threadIdx.y;
  for (int i = 0; i < 4; i++)
    tile[ty + 8 * i][tx] = in[(size_t)(r0 + ty + 8 * i) * Cin + c0 + tx];
  __syncthreads();
  for (int i = 0; i < 4; i++)
    out[(size_t)(c0 + ty + 8 * i) * R + r0 + tx] = f2b(tile[tx][ty + 8 * i]);
}

// ---------- V transpose: QKV (4096,3072) bf16 -> Vt (B*H, 64, 2048) bf16 ----------
__global__ __launch_bounds__(256) void transpose_v_kernel(
    const ushort_t* __restrict__ qkv, ushort_t* __restrict__ vt) {
  __shared__ ushort_t tile[32][33];
  int bh = blockIdx.z;
  int b = bh >> 4, h = bh & 15;
  int d0 = blockIdx.x * 32, t0 = blockIdx.y * 32;
  int tx = threadIdx.x, ty = threadIdx.y;
  for (int i = 0; i < 4; i++)
    tile[ty + 8 * i][tx] =
        qkv[(size_t)(b * 2048 + t0 + ty + 8 * i) * 3072 + 2048 + h * 64 + d0 + tx];
  __syncthreads();
  for (int i = 0; i < 4; i++)
    vt[(size_t)(bh * 64 + d0 + ty + 8 * i) * 2048 + t0 + tx] = tile[tx][ty + 8 * i];
}

// ---------- GEMM: out(M,N) = A(M,K) @ Bt(N,K)^T, bf16 in, optional bias/resid/relu ----------
// flags: 1 = relu, 2 = bf16 output (else fp32)
__global__ __launch_bounds__(256) void gemm_bt_kernel(
    const ushort_t* __restrict__ A, const ushort_t* __restrict__ Bt,
    const float* __restrict__ bias, const float* __restrict__ resid,
    void* __restrict__ outv, int M, int N, int K, int flags) {
  __shared__ ushort_t Als[128 * 32];
  __shared__ ushort_t Bls[128 * 32];
  int tid = threadIdx.x, w = tid >> 6, lane = tid & 63, quad = lane >> 4, l16 = lane & 15;
  int bn0 = blockIdx.x * 128, bm0 = blockIdx.y * 128;
  int wm = (w >> 1) * 64, wn = (w & 1) * 64;
  f32x4 acc[4][4];
  for (int i = 0; i < 4; i++)
    for (int j = 0; j < 4; j++) acc[i][j] = f32x4{0.f, 0.f, 0.f, 0.f};
  const ushort_t* Ag = A + (size_t)bm0 * K;
  const ushort_t* Bg = Bt + (size_t)bn0 * K;
  for (int k0 = 0; k0 < K; k0 += 32) {
    for (int it = 0; it < 2; it++) {
      int c = (w * 2 + it) * 64 + lane;
      int r = c >> 2, co = (c & 3) * 8;
      async16(Ag + (size_t)r * K + k0 + co, &Als[(w * 2 + it) * 512]);
      async16(Bg + (size_t)r * K + k0 + co, &Bls[(w * 2 + it) * 512]);
    }
    __syncthreads();
    bf16x8 af[4], bf[4];
    for (int i = 0; i < 4; i++)
      af[i] = *(const bf16x8*)&Als[(wm + i * 16 + l16) * 32 + quad * 8];
    for (int j = 0; j < 4; j++)
      bf[j] = *(const bf16x8*)&Bls[(wn + j * 16 + l16) * 32 + quad * 8];
    for (int i = 0; i < 4; i++)
      for (int j = 0; j < 4; j++)
        acc[i][j] = __builtin_amdgcn_mfma_f32_16x16x32_bf16(af[i], bf[j], acc[i][j], 0, 0, 0);
    __syncthreads();
  }
  for (int i = 0; i < 4; i++)
    for (int j = 0; j < 4; j++)
      for (int r = 0; r < 4; r++) {
        int row = bm0 + wm + i * 16 + quad * 4 + r;
        int col = bn0 + wn + j * 16 + l16;
        float v = acc[i][j][r];
        if (bias) v += bias[col];
        if (resid) v += resid[(size_t)row * N + col];
        if (flags & 1) v = fmaxf(v, 0.f);
        if (flags & 2)
          ((ushort_t*)outv)[(size_t)row * N + col] = f2b(v);
        else
          ((float*)outv)[(size_t)row * N + col] = v;
      }
}

// ---------- causal flash attention ----------
// grid: (T/64, B*H). block 256 = 4 waves; wave w handles q rows [q0+16w, q0+16w+16)
// QKV (4096,3072) bf16 [Q | K | V], Vt (B*H,64,2048) bf16, out (4096,1024) bf16
__global__ __launch_bounds__(256) void attn_kernel(
    const ushort_t* __restrict__ qkv, const ushort_t* __restrict__ vt,
    ushort_t* __restrict__ out) {
  const int T = 2048, CC = 3072;
  __shared__ ushort_t Kls[64 * 72];      // padded stride 72 (144B) -> 2-way max
  __shared__ ushort_t Vls[64 * 72];      // (d, s_local)
  __shared__ ushort_t Pls[4][16 * 72];   // per-wave P scratch
  int qblk = blockIdx.x, bh = blockIdx.y;
  int b = bh >> 4, h = bh & 15;
  int q0 = qblk * 64;
  int tid = threadIdx.x, w = tid >> 6, lane = tid & 63, quad = lane >> 4, l16 = lane & 15;
  // Q fragments (A-layout: m=l16, k=quad*8+j), resident for whole block
  bf16x8 aq[2];
  {
    int tq = q0 + w * 16 + l16;
    const ushort_t* qp = qkv + (size_t)(b * T + tq) * CC + h * 64 + quad * 8;
    aq[0] = *(const bf16x8*)qp;
    aq[1] = *(const bf16x8*)(qp + 32);
  }
  f32x4 O[4];
  for (int i = 0; i < 4; i++) O[i] = f32x4{0.f, 0.f, 0.f, 0.f};
  float mrun[4] = {-1e30f, -1e30f, -1e30f, -1e30f};
  float lrun[4] = {0.f, 0.f, 0.f, 0.f};
  for (int kb = 0; kb <= qblk; kb++) {
    int s0 = kb * 64;
    // stage K chunk (s,d) and Vt chunk (d,s) into padded LDS
    for (int i = 0; i < 2; i++) {
      int c = tid + i * 256;
      int r = c >> 3, co = (c & 7) * 8;
      bf16x8 kk = *(const bf16x8*)&qkv[(size_t)(b * T + s0 + r) * CC + 1024 + h * 64 + co];
      *(bf16x8*)&Kls[r * 72 + co] = kk;
      bf16x8 vv = *(const bf16x8*)&vt[(size_t)(bh * 64 + r) * T + s0 + co];
      *(bf16x8*)&Vls[r * 72 + co] = vv;
    }
    __syncthreads();
    // S = Q K^T for 4 column tiles
    f32x4 sacc[4];
    for (int tn = 0; tn < 4; tn++) {
      sacc[tn] = f32x4{0.f, 0.f, 0.f, 0.f};
      for (int ks = 0; ks < 2; ks++) {
        bf16x8 bfr = *(const bf16x8*)&Kls[(tn * 16 + l16) * 72 + ks * 32 + quad * 8];
        sacc[tn] = __builtin_amdgcn_mfma_f32_16x16x32_bf16(aq[ks], bfr, sacc[tn], 0, 0, 0);
      }
    }
    bool diag = (kb == qblk);
    // online softmax: lane holds rows quad*4+r, cols tn*16+l16
    for (int r = 0; r < 4; r++) {
      int trow = q0 + w * 16 + quad * 4 + r;
      float sv[4];
      float vmax = -1e30f;
      for (int tn = 0; tn < 4; tn++) {
        float sc = sacc[tn][r] * 0.03125f;  // * C^-0.5 (faithful: 1/32)
        int scol = s0 + tn * 16 + l16;
        if (diag && scol > trow) sc = -1e30f;
        sv[tn] = sc;
        vmax = fmaxf(vmax, sc);
      }
      for (int off = 1; off < 16; off <<= 1) vmax = fmaxf(vmax, __shfl_xor(vmax, off));
      float mnew = fmaxf(mrun[r], vmax);
      float alpha = __expf(mrun[r] - mnew);
      mrun[r] = mnew;
      float psum = 0.f;
      for (int tn = 0; tn < 4; tn++) {
        float p = __expf(sv[tn] - mnew);
        psum += p;
        Pls[w][(quad * 4 + r) * 72 + tn * 16 + l16] = f2b(p);
      }
      for (int off = 1; off < 16; off <<= 1) psum += __shfl_xor(psum, off);
      lrun[r] = lrun[r] * alpha + psum;
      for (int dt = 0; dt < 4; dt++) O[dt][r] *= alpha;
    }
    __syncthreads();  // P visible; also keeps waves aligned
    // O += P @ V
    for (int ks = 0; ks < 2; ks++) {
      bf16x8 af = *(const bf16x8*)&Pls[w][l16 * 72 + ks * 32 + quad * 8];
      for (int dt = 0; dt < 4; dt++) {
        bf16x8 bfr = *(const bf16x8*)&Vls[(dt * 16 + l16) * 72 + ks * 32 + quad * 8];
        O[dt] = __builtin_amdgcn_mfma_f32_16x16x32_bf16(af, bfr, O[dt], 0, 0, 0);
      }
    }
    __syncthreads();  // all reads of Kls/Vls done before next stage
  }
  for (int r = 0; r < 4; r++) {
    int trow = q0 + w * 16 + quad * 4 + r;
    float inv = 1.f / lrun[r];
    for (int dt = 0; dt < 4; dt++)
      out[(size_t)(b * T + trow) * 1024 + h * 64 + dt * 16 + l16] = f2b(O[dt][r] * inv);
  }
}

// ---------- host ----------
extern "C" void kernel_launch(void* const* d_in, const int* in_sizes, int n_in,
                              void* d_out, int out_size, void* d_ws, size_t ws_size,
                              hipStream_t stream) {
  const int B = 2, T = 2048, C = 1024, H = 16, D = 64, FF = 4096;
  const int M = B * T;  // 4096
  const float* x   = (const float*)d_in[0];
  const float* Wq  = (const float*)d_in[1];
  const float* Wk  = (const float*)d_in[2];
  const float* Wv  = (const float*)d_in[3];
  const float* Wo  = (const float*)d_in[4];
  const float* bo  = (const float*)d_in[5];
  const float* W1  = (const float*)d_in[6];
  const float* b1  = (const float*)d_in[7];
  const float* W2  = (const float*)d_in[8];
  const float* b2  = (const float*)d_in[9];
  const float* g1  = (const float*)d_in[10];
  const float* be1 = (const float*)d_in[11];
  const float* g2  = (const float*)d_in[12];
  const float* be2 = (const float*)d_in[13];
  float* out = (float*)d_out;

  char* ws = (char*)d_ws;
  size_t off = 0;
  auto alloc = [&](size_t bytes) {
    void* p = ws + off;
    off += (bytes + 255) & ~(size_t)255;
    return p;
  };
  ushort_t* qkvt = (ushort_t*)alloc((size_t)3 * C * C * 2);  // (3072,1024) W_qkv^T
  ushort_t* wot  = (ushort_t*)alloc((size_t)C * C * 2);      // (1024,1024) Wo^T
  ushort_t* w1t  = (ushort_t*)alloc((size_t)FF * C * 2);     // (4096,1024) W1^T
  ushort_t* w2t  = (ushort_t*)alloc((size_t)C * FF * 2);     // (1024,4096) W2^T
  ushort_t* hbuf = (ushort_t*)alloc((size_t)M * C * 2);      // LN out (reused LN2)
  ushort_t* big  = (ushort_t*)alloc((size_t)M * FF * 2);     // QKV (4096,3072), later ff1 (4096,4096)
  ushort_t* vtb  = (ushort_t*)alloc((size_t)M * C * 2);      // Vt (B*H,64,2048)
  ushort_t* aout = (ushort_t*)alloc((size_t)M * C * 2);      // attention out bf16
  float*    x2   = (float*)alloc((size_t)M * C * 4);         // post-attn residual fp32

  dim3 tb(32, 8);
  // weight prep: cast + transpose to (N,K) bf16
  transpose_cast_kernel<<<dim3(D / 32, C / 32, H), tb, 0, stream>>>(Wq, qkvt, C, D);
  transpose_cast_kernel<<<dim3(D / 32, C / 32, H), tb, 0, stream>>>(Wk, qkvt + (size_t)C * C, C, D);
  transpose_cast_kernel<<<dim3(D / 32, C / 32, H), tb, 0, stream>>>(Wv, qkvt + (size_t)2 * C * C, C, D);
  transpose_cast_kernel<<<dim3(C / 32, C / 32, 1), tb, 0, stream>>>(Wo, wot, C, C);
  transpose_cast_kernel<<<dim3(FF / 32, C / 32, 1), tb, 0, stream>>>(W1, w1t, C, FF);
  transpose_cast_kernel<<<dim3(C / 32, FF / 32, 1), tb, 0, stream>>>(W2, w2t, FF, C);
  // LN1
  ln_kernel<<<M, 256, 0, stream>>>(x, g1, be1, hbuf);
  // QKV = h @ Wqkv^T  -> bf16
  gemm_bt_kernel<<<dim3(3 * C / 128, M / 128), 256, 0, stream>>>(
      hbuf, qkvt, nullptr, nullptr, big, M, 3 * C, C, 2);
  // V transpose per head
  transpose_v_kernel<<<dim3(2, T / 32, B * H), tb, 0, stream>>>(big, vtb);
  // attention
  attn_kernel<<<dim3(T / 64, B * H), 256, 0, stream>>>(big, vtb, aout);
  // x2 = attn @ Wo^T + bo + x  (fp32)
  gemm_bt_kernel<<<dim3(C / 128, M / 128), 256, 0, stream>>>(
      aout, wot, bo, x, x2, M, C, C, 0);
  // LN2
  ln_kernel<<<M, 256, 0, stream>>>(x2, g2, be2, hbuf);
  // ff1 = relu(h2 @ W1^T + b1) -> bf16
  gemm_bt_kernel<<<dim3(FF / 128, M / 128), 256, 0, stream>>>(
      hbuf, w1t, b1, nullptr, big, M, FF, C, 1 | 2);
  // out = ff1 @ W2^T + b2 + x2 (fp32)
  gemm_bt_kernel<<<dim3(C / 128, M / 128), 256, 0, stream>>>(
      big, w2t, b2, x2, out, M, C, FF, 0);
}

// Round 2
// 442.943 us; speedup vs baseline: 2.9206x; 2.9206x over previous
//
#include <hip/hip_runtime.h>
#include <stdint.h>

typedef unsigned short ushort_t;
typedef __attribute__((ext_vector_type(8))) short bf16x8;   // 8 bf16 in 4 VGPRs
typedef __attribute__((ext_vector_type(4))) float f32x4;

// ---------- helpers ----------
__device__ __forceinline__ unsigned short f2b(float f) {
  unsigned u = __float_as_uint(f);
  u += 0x7fffu + ((u >> 16) & 1u);   // round-to-nearest-even
  return (unsigned short)(u >> 16);
}

__device__ __forceinline__ void async16(const void* g, void* l) {
  // dest = wave-uniform LDS base + lane*16 (pass uniform base)
  __builtin_amdgcn_global_load_lds(
      (const __attribute__((address_space(1))) void*)g,
      (__attribute__((address_space(3))) void*)l, 16, 0, 0);
}

// ---------- LayerNorm (fp32 in -> bf16 out), one block per row, C=1024 ----------
__global__ __launch_bounds__(256) void ln_kernel(
    const float* __restrict__ x, const float* __restrict__ g,
    const float* __restrict__ be, ushort_t* __restrict__ out) {
  const int C = 1024;
  int row = blockIdx.x;
  const float4* xr = (const float4*)(x + (size_t)row * C);
  int tid = threadIdx.x;
  float4 v = xr[tid];
  float s = v.x + v.y + v.z + v.w;
  float sq = v.x * v.x + v.y * v.y + v.z * v.z + v.w * v.w;
  #pragma unroll
  for (int off = 32; off > 0; off >>= 1) {
    s += __shfl_xor(s, off);
    sq += __shfl_xor(sq, off);
  }
  __shared__ float ss[4], ssq[4];
  int wv = tid >> 6;
  if ((tid & 63) == 0) { ss[wv] = s; ssq[wv] = sq; }
  __syncthreads();
  s = ss[0] + ss[1] + ss[2] + ss[3];
  sq = ssq[0] + ssq[1] + ssq[2] + ssq[3];
  float mu = s * (1.f / C);
  float var = sq * (1.f / C) - mu * mu;
  float rs = rsqrtf(var + 1e-5f);
  float4 gv = ((const float4*)g)[tid];
  float4 bv = ((const float4*)be)[tid];
  ushort4 o;
  o.x = f2b((v.x - mu) * rs * gv.x + bv.x);
  o.y = f2b((v.y - mu) * rs * gv.y + bv.y);
  o.z = f2b((v.z - mu) * rs * gv.z + bv.z);
  o.w = f2b((v.w - mu) * rs * gv.w + bv.w);
  ((ushort4*)(out + (size_t)row * C))[tid] = o;
}

// ---------- batched transpose + fp32->bf16 cast: in (bz,R,Cin) -> out (bz,Cin,R) ----------
__global__ __launch_bounds__(256) void transpose_cast_kernel(
    const float* __restrict__ in, ushort_t* __restrict__ out, int R, int Cin) {
  __shared__ float tile[32][33];
  int bz = blockIdx.z;
  in += (size_t)bz * R * Cin;
  out += (size_t)bz * R * Cin;
  int c0 = blockIdx.x * 32, r0 = blockIdx.y * 32;
  int tx = threadIdx.x, ty = threadIdx.y;
  #pragma unroll
  for (int i = 0; i < 4; i++)
    tile[ty + 8 * i][tx] = in[(size_t)(r0 + ty + 8 * i) * Cin + c0 + tx];
  __syncthreads();
  #pragma unroll
  for (int i = 0; i < 4; i++)
    out[(size_t)(c0 + ty + 8 * i) * R + r0 + tx] = f2b(tile[tx][ty + 8 * i]);
}

// ---------- V transpose: QKV (4096,3072) bf16 -> Vt (B*H, 64, 2048) bf16 ----------
__global__ __launch_bounds__(256) void transpose_v_kernel(
    const ushort_t* __restrict__ qkv, ushort_t* __restrict__ vt) {
  __shared__ ushort_t tile[32][33];
  int bh = blockIdx.z;
  int b = bh >> 4, h = bh & 15;
  int d0 = blockIdx.x * 32, t0 = blockIdx.y * 32;
  int tx = threadIdx.x, ty = threadIdx.y;
  #pragma unroll
  for (int i = 0; i < 4; i++)
    tile[ty + 8 * i][tx] =
        qkv[(size_t)(b * 2048 + t0 + ty + 8 * i) * 3072 + 2048 + h * 64 + d0 + tx];
  __syncthreads();
  #pragma unroll
  for (int i = 0; i < 4; i++)
    vt[(size_t)(bh * 64 + d0 + ty + 8 * i) * 2048 + t0 + tx] = tile[tx][ty + 8 * i];
}

// ---------- GEMM: out(M,N) = A(M,K) @ Bt(N,K)^T, bf16 in ----------
// Compile-time N, K, FLAGS. FLAGS: 1 = relu, 2 = bf16 output (else fp32),
// 4 = add bias, 8 = add resid. M = 4096 always (runtime grid covers it).
template <int N, int K, int FLAGS>
__global__ __launch_bounds__(256, 2) void gemm_bt_kernel(
    const ushort_t* __restrict__ A, const ushort_t* __restrict__ Bt,
    const float* __restrict__ bias, const float* __restrict__ resid,
    void* __restrict__ outv) {
  __shared__ ushort_t Als[128 * 32];
  __shared__ ushort_t Bls[128 * 32];
  int tid = threadIdx.x, w = tid >> 6, lane = tid & 63, quad = lane >> 4, l16 = lane & 15;
  int bn0 = blockIdx.x * 128, bm0 = blockIdx.y * 128;
  int wm = (w >> 1) * 64, wn = (w & 1) * 64;
  f32x4 acc[4][4];
  #pragma unroll
  for (int i = 0; i < 4; i++)
    #pragma unroll
    for (int j = 0; j < 4; j++) acc[i][j] = f32x4{0.f, 0.f, 0.f, 0.f};
  const ushort_t* Ag = A + (size_t)bm0 * K;
  const ushort_t* Bg = Bt + (size_t)bn0 * K;
  // per-lane staging coords (constant across K-loop)
  int c0 = w * 128 + lane;          // it=0 chunk id
  int r0s = c0 >> 2, co0 = (c0 & 3) * 8;
  int c1 = c0 + 64;                 // it=1 chunk id
  int r1s = c1 >> 2, co1 = (c1 & 3) * 8;
  for (int k0 = 0; k0 < K; k0 += 32) {
    async16(Ag + (size_t)r0s * K + k0 + co0, &Als[w * 1024]);
    async16(Bg + (size_t)r0s * K + k0 + co0, &Bls[w * 1024]);
    async16(Ag + (size_t)r1s * K + k0 + co1, &Als[w * 1024 + 512]);
    async16(Bg + (size_t)r1s * K + k0 + co1, &Bls[w * 1024 + 512]);
    __syncthreads();
    bf16x8 af[4], bf[4];
    #pragma unroll
    for (int i = 0; i < 4; i++)
      af[i] = *(const bf16x8*)&Als[(wm + i * 16 + l16) * 32 + quad * 8];
    #pragma unroll
    for (int j = 0; j < 4; j++)
      bf[j] = *(const bf16x8*)&Bls[(wn + j * 16 + l16) * 32 + quad * 8];
    #pragma unroll
    for (int i = 0; i < 4; i++)
      #pragma unroll
      for (int j = 0; j < 4; j++)
        acc[i][j] = __builtin_amdgcn_mfma_f32_16x16x32_bf16(af[i], bf[j], acc[i][j], 0, 0, 0);
    __syncthreads();
  }
  #pragma unroll
  for (int i = 0; i < 4; i++)
    #pragma unroll
    for (int j = 0; j < 4; j++)
      #pragma unroll
      for (int r = 0; r < 4; r++) {
        int row = bm0 + wm + i * 16 + quad * 4 + r;
        int col = bn0 + wn + j * 16 + l16;
        float v = acc[i][j][r];
        if constexpr (FLAGS & 4) v += bias[col];
        if constexpr (FLAGS & 8) v += resid[(size_t)row * N + col];
        if constexpr (FLAGS & 1) v = fmaxf(v, 0.f);
        if constexpr ((FLAGS & 2) != 0)
          ((ushort_t*)outv)[(size_t)row * N + col] = f2b(v);
        else
          ((float*)outv)[(size_t)row * N + col] = v;
      }
}

// ---------- causal flash attention ----------
// grid: (T/64, B*H). block 256 = 4 waves; wave w handles q rows [q0+16w, q0+16w+16)
// QKV (4096,3072) bf16 [Q | K | V], Vt (B*H,64,2048) bf16, out (4096,1024) bf16
__global__ __launch_bounds__(256) void attn_kernel(
    const ushort_t* __restrict__ qkv, const ushort_t* __restrict__ vt,
    ushort_t* __restrict__ out) {
  const int T = 2048, CC = 3072;
  __shared__ ushort_t Kls[64 * 72];      // padded stride 72 (144B)
  __shared__ ushort_t Vls[64 * 72];      // (d, s_local)
  __shared__ ushort_t Pls[4][16 * 72];   // per-wave P scratch
  int qblk = blockIdx.x, bh = blockIdx.y;
  int b = bh >> 4, h = bh & 15;
  int q0 = qblk * 64;
  int tid = threadIdx.x, w = tid >> 6, lane = tid & 63, quad = lane >> 4, l16 = lane & 15;
  bf16x8 aq[2];
  {
    int tq = q0 + w * 16 + l16;
    const ushort_t* qp = qkv + (size_t)(b * T + tq) * CC + h * 64 + quad * 8;
    aq[0] = *(const bf16x8*)qp;
    aq[1] = *(const bf16x8*)(qp + 32);
  }
  f32x4 O[4];
  #pragma unroll
  for (int i = 0; i < 4; i++) O[i] = f32x4{0.f, 0.f, 0.f, 0.f};
  float mrun[4] = {-1e30f, -1e30f, -1e30f, -1e30f};
  float lrun[4] = {0.f, 0.f, 0.f, 0.f};
  for (int kb = 0; kb <= qblk; kb++) {
    int s0 = kb * 64;
    #pragma unroll
    for (int i = 0; i < 2; i++) {
      int c = tid + i * 256;
      int r = c >> 3, co = (c & 7) * 8;
      bf16x8 kk = *(const bf16x8*)&qkv[(size_t)(b * T + s0 + r) * CC + 1024 + h * 64 + co];
      *(bf16x8*)&Kls[r * 72 + co] = kk;
      bf16x8 vv = *(const bf16x8*)&vt[(size_t)(bh * 64 + r) * T + s0 + co];
      *(bf16x8*)&Vls[r * 72 + co] = vv;
    }
    __syncthreads();
    f32x4 sacc[4];
    #pragma unroll
    for (int tn = 0; tn < 4; tn++) {
      sacc[tn] = f32x4{0.f, 0.f, 0.f, 0.f};
      #pragma unroll
      for (int ks = 0; ks < 2; ks++) {
        bf16x8 bfr = *(const bf16x8*)&Kls[(tn * 16 + l16) * 72 + ks * 32 + quad * 8];
        sacc[tn] = __builtin_amdgcn_mfma_f32_16x16x32_bf16(aq[ks], bfr, sacc[tn], 0, 0, 0);
      }
    }
    bool diag = (kb == qblk);
    #pragma unroll
    for (int r = 0; r < 4; r++) {
      int trow = q0 + w * 16 + quad * 4 + r;
      float sv[4];
      float vmax = -1e30f;
      #pragma unroll
      for (int tn = 0; tn < 4; tn++) {
        float sc = sacc[tn][r] * 0.03125f;  // * C^-0.5 (faithful: 1/32)
        int scol = s0 + tn * 16 + l16;
        if (diag && scol > trow) sc = -1e30f;
        sv[tn] = sc;
        vmax = fmaxf(vmax, sc);
      }
      #pragma unroll
      for (int off = 1; off < 16; off <<= 1) vmax = fmaxf(vmax, __shfl_xor(vmax, off));
      float mnew = fmaxf(mrun[r], vmax);
      float alpha = __expf(mrun[r] - mnew);
      mrun[r] = mnew;
      float psum = 0.f;
      #pragma unroll
      for (int tn = 0; tn < 4; tn++) {
        float p = __expf(sv[tn] - mnew);
        psum += p;
        Pls[w][(quad * 4 + r) * 72 + tn * 16 + l16] = f2b(p);
      }
      #pragma unroll
      for (int off = 1; off < 16; off <<= 1) psum += __shfl_xor(psum, off);
      lrun[r] = lrun[r] * alpha + psum;
      #pragma unroll
      for (int dt = 0; dt < 4; dt++) O[dt][r] *= alpha;
    }
    __syncthreads();
    #pragma unroll
    for (int ks = 0; ks < 2; ks++) {
      bf16x8 af = *(const bf16x8*)&Pls[w][l16 * 72 + ks * 32 + quad * 8];
      #pragma unroll
      for (int dt = 0; dt < 4; dt++) {
        bf16x8 bfr = *(const bf16x8*)&Vls[(dt * 16 + l16) * 72 + ks * 32 + quad * 8];
        O[dt] = __builtin_amdgcn_mfma_f32_16x16x32_bf16(af, bfr, O[dt], 0, 0, 0);
      }
    }
    __syncthreads();
  }
  #pragma unroll
  for (int r = 0; r < 4; r++) {
    int trow = q0 + w * 16 + quad * 4 + r;
    float inv = 1.f / lrun[r];
    #pragma unroll
    for (int dt = 0; dt < 4; dt++)
      out[(size_t)(b * T + trow) * 1024 + h * 64 + dt * 16 + l16] = f2b(O[dt][r] * inv);
  }
}

// ---------- host ----------
extern "C" void kernel_launch(void* const* d_in, const int* in_sizes, int n_in,
                              void* d_out, int out_size, void* d_ws, size_t ws_size,
                              hipStream_t stream) {
  const int B = 2, T = 2048, C = 1024, H = 16, D = 64, FF = 4096;
  const int M = B * T;  // 4096
  const float* x   = (const float*)d_in[0];
  const float* Wq  = (const float*)d_in[1];
  const float* Wk  = (const float*)d_in[2];
  const float* Wv  = (const float*)d_in[3];
  const float* Wo  = (const float*)d_in[4];
  const float* bo  = (const float*)d_in[5];
  const float* W1  = (const float*)d_in[6];
  const float* b1  = (const float*)d_in[7];
  const float* W2  = (const float*)d_in[8];
  const float* b2  = (const float*)d_in[9];
  const float* g1  = (const float*)d_in[10];
  const float* be1 = (const float*)d_in[11];
  const float* g2  = (const float*)d_in[12];
  const float* be2 = (const float*)d_in[13];
  float* out = (float*)d_out;

  char* ws = (char*)d_ws;
  size_t off = 0;
  auto alloc = [&](size_t bytes) {
    void* p = ws + off;
    off += (bytes + 255) & ~(size_t)255;
    return p;
  };
  ushort_t* qkvt = (ushort_t*)alloc((size_t)3 * C * C * 2);  // (3072,1024) W_qkv^T
  ushort_t* wot  = (ushort_t*)alloc((size_t)C * C * 2);      // (1024,1024) Wo^T
  ushort_t* w1t  = (ushort_t*)alloc((size_t)FF * C * 2);     // (4096,1024) W1^T
  ushort_t* w2t  = (ushort_t*)alloc((size_t)C * FF * 2);     // (1024,4096) W2^T
  ushort_t* hbuf = (ushort_t*)alloc((size_t)M * C * 2);      // LN out (reused LN2)
  ushort_t* big  = (ushort_t*)alloc((size_t)M * FF * 2);     // QKV (4096,3072), later ff1
  ushort_t* vtb  = (ushort_t*)alloc((size_t)M * C * 2);      // Vt (B*H,64,2048)
  ushort_t* aout = (ushort_t*)alloc((size_t)M * C * 2);      // attention out bf16
  float*    x2   = (float*)alloc((size_t)M * C * 4);         // post-attn residual fp32

  dim3 tb(32, 8);
  transpose_cast_kernel<<<dim3(D / 32, C / 32, H), tb, 0, stream>>>(Wq, qkvt, C, D);
  transpose_cast_kernel<<<dim3(D / 32, C / 32, H), tb, 0, stream>>>(Wk, qkvt + (size_t)C * C, C, D);
  transpose_cast_kernel<<<dim3(D / 32, C / 32, H), tb, 0, stream>>>(Wv, qkvt + (size_t)2 * C * C, C, D);
  transpose_cast_kernel<<<dim3(C / 32, C / 32, 1), tb, 0, stream>>>(Wo, wot, C, C);
  transpose_cast_kernel<<<dim3(FF / 32, C / 32, 1), tb, 0, stream>>>(W1, w1t, C, FF);
  transpose_cast_kernel<<<dim3(C / 32, FF / 32, 1), tb, 0, stream>>>(W2, w2t, FF, C);
  ln_kernel<<<M, 256, 0, stream>>>(x, g1, be1, hbuf);
  // QKV = h @ Wqkv^T -> bf16
  gemm_bt_kernel<3072, 1024, 2><<<dim3(3072 / 128, M / 128), 256, 0, stream>>>(
      hbuf, qkvt, nullptr, nullptr, big);
  transpose_v_kernel<<<dim3(2, T / 32, B * H), tb, 0, stream>>>(big, vtb);
  attn_kernel<<<dim3(T / 64, B * H), 256, 0, stream>>>(big, vtb, aout);
  // x2 = attn @ Wo^T + bo + x (fp32)
  gemm_bt_kernel<1024, 1024, 4 | 8><<<dim3(1024 / 128, M / 128), 256, 0, stream>>>(
      aout, wot, bo, x, x2);
  ln_kernel<<<M, 256, 0, stream>>>(x2, g2, be2, hbuf);
  // ff1 = relu(h2 @ W1^T + b1) -> bf16
  gemm_bt_kernel<4096, 1024, 1 | 2 | 4><<<dim3(4096 / 128, M / 128), 256, 0, stream>>>(
      hbuf, w1t, b1, nullptr, big);
  // out = ff1 @ W2^T + b2 + x2 (fp32)
  gemm_bt_kernel<1024, 4096, 4 | 8><<<dim3(1024 / 128, M / 128), 256, 0, stream>>>(
      big, w2t, b2, x2, out);
}